// Round 1
// baseline (121329.358 us; speedup 1.0000x reference)
//
#include <hip/hip_runtime.h>
#include <hip/hip_bf16.h>

#define T_LEN 4096
#define HID   1024
#define NTAG  18
#define BEGIN_TAG 16
#define END_TAG   17
#define NEGV  -10000.0f

// workspace layout (float offsets)
#define OFF_PRE_F  0ull
#define OFF_PRE_B  16777216ull
#define OFF_HS_F   33554432ull
#define OFF_HS_B   37748736ull
#define OFF_FRAMES 41943040ull
#define OFF_FLAGS  42016768ull   // 128 x u32 lives here

// ---------------------------------------------------------------- init flags
__global__ void init_flags_kernel(unsigned int* flags) {
    if (threadIdx.x < 128) flags[threadIdx.x] = 0u;
}

// -------------------------------------------------- pre = emb[words] @ W_ih^T + b
// C[t,r] = sum_e emb[words[t],e] * W[r,e] + b[r];  M=4096 (t), N=4096 (r), K=512
// 128x128 tile, BK=32, 256 threads, 8x8 microtile.
__global__ __launch_bounds__(256) void pre_gemm_kernel(
    const int*   __restrict__ words,
    const float* __restrict__ emb,
    const float* __restrict__ Wf, const float* __restrict__ bf,
    const float* __restrict__ Wb, const float* __restrict__ bb,
    float* __restrict__ pre_f, float* __restrict__ pre_b)
{
    const int dir = blockIdx.z;
    const float* W    = dir ? Wb : Wf;
    const float* bias = dir ? bb : bf;
    float* pre        = dir ? pre_b : pre_f;
    const int tb = blockIdx.x * 128;
    const int nb = blockIdx.y * 128;
    const int tid = threadIdx.x;

    __shared__ float As[32][128];
    __shared__ float Bs[32][128];

    float acc[8][8];
#pragma unroll
    for (int i = 0; i < 8; ++i)
#pragma unroll
        for (int j = 0; j < 8; ++j) acc[i][j] = 0.f;

    const int row   = tid >> 1;           // 0..127
    const int ebase = (tid & 1) * 16;     // 0 / 16
    const int tm = tid >> 4;              // 0..15
    const int tn = tid & 15;              // 0..15

    const int wrow = words[tb + row];
    const float* aSrc = emb + (size_t)wrow * 512 + ebase;
    const float* bSrc = W   + (size_t)(nb + row) * 512 + ebase;

    for (int kk = 0; kk < 512; kk += 32) {
#pragma unroll
        for (int q = 0; q < 4; ++q) {
            float4 av = *(const float4*)(aSrc + kk + q * 4);
            float4 bv = *(const float4*)(bSrc + kk + q * 4);
            As[ebase + q*4 + 0][row] = av.x;
            As[ebase + q*4 + 1][row] = av.y;
            As[ebase + q*4 + 2][row] = av.z;
            As[ebase + q*4 + 3][row] = av.w;
            Bs[ebase + q*4 + 0][row] = bv.x;
            Bs[ebase + q*4 + 1][row] = bv.y;
            Bs[ebase + q*4 + 2][row] = bv.z;
            Bs[ebase + q*4 + 3][row] = bv.w;
        }
        __syncthreads();
#pragma unroll 4
        for (int k = 0; k < 32; ++k) {
            float a[8], b[8];
            *(float4*)&a[0] = *(const float4*)&As[k][tm*8];
            *(float4*)&a[4] = *(const float4*)&As[k][tm*8 + 4];
            *(float4*)&b[0] = *(const float4*)&Bs[k][tn*8];
            *(float4*)&b[4] = *(const float4*)&Bs[k][tn*8 + 4];
#pragma unroll
            for (int i = 0; i < 8; ++i)
#pragma unroll
                for (int j = 0; j < 8; ++j)
                    acc[i][j] = fmaf(a[i], b[j], acc[i][j]);
        }
        __syncthreads();
    }

    float bvals[8];
#pragma unroll
    for (int j = 0; j < 8; ++j) bvals[j] = bias[nb + tn*8 + j];

#pragma unroll
    for (int i = 0; i < 8; ++i) {
        const size_t r = (size_t)(tb + tm*8 + i);
        float o[8];
#pragma unroll
        for (int j = 0; j < 8; ++j) o[j] = acc[i][j] + bvals[j];
        *(float4*)(pre + r*4096 + nb + tn*8)     = *(float4*)&o[0];
        *(float4*)(pre + r*4096 + nb + tn*8 + 4) = *(float4*)&o[4];
    }
}

// -------------------------------------------------------------- recurrence
// 128 WGs: wg>>6 = direction, wg&63 = unit-group (16 hidden units).
// 512 threads = 8 waves: wave w2 -> gate (w2&3), half (w2>>2) => 8 rows/wave.
// Weights in VGPRs: wreg[8][16], lane l covers k = l*16 + m.
// Cross-WG sync: per-WG monotonic step flag, release/acquire, agent scope.
__global__ __launch_bounds__(512, 2) void rec_kernel(
    const float* __restrict__ Whh_f, const float* __restrict__ Whh_b,
    const float* __restrict__ pre_f, const float* __restrict__ pre_b,
    const float* __restrict__ h0, const float* __restrict__ c0,
    float* __restrict__ hs_f, float* __restrict__ hs_b,
    unsigned int* __restrict__ flags)
{
    const int wg  = blockIdx.x;
    const int dir = wg >> 6;
    const int g   = wg & 63;
    const int u0  = g * 16;
    const int tid = threadIdx.x;
    const int w2  = tid >> 6;      // 0..7
    const int l   = tid & 63;
    const int gate = w2 & 3;
    const int half = w2 >> 2;

    const float* Whh = dir ? Whh_b : Whh_f;
    const float* pre = dir ? pre_b : pre_f;
    float* hs        = dir ? hs_b  : hs_f;
    unsigned int* myf = flags + dir * 64;

    float wreg[8][16];
#pragma unroll
    for (int r = 0; r < 8; ++r) {
        const float* wr = Whh + (size_t)(gate*HID + u0 + half*8 + r) * HID + l*16;
#pragma unroll
        for (int q = 0; q < 4; ++q) {
            float4 v = *(const float4*)(wr + q*4);
            wreg[r][q*4+0] = v.x; wreg[r][q*4+1] = v.y;
            wreg[r][q*4+2] = v.z; wreg[r][q*4+3] = v.w;
        }
    }

    float creg = 0.f;
    if (w2 == 0 && l < 16) creg = c0[dir*HID + u0 + l];

    __shared__ float zbuf[64];

    for (int s = 0; s < T_LEN; ++s) {
        const int t = dir ? (T_LEN - 1 - s) : s;

        if (s > 0) {
            while (true) {
                unsigned f = __hip_atomic_load(&myf[l], __ATOMIC_ACQUIRE,
                                               __HIP_MEMORY_SCOPE_AGENT);
                if (__all((int)(f >= (unsigned)s))) break;
                __builtin_amdgcn_s_sleep(1);
            }
        }

        const float* hp = (s == 0) ? (h0 + dir*HID)
                                   : (hs + (size_t)(dir ? (t + 1) : (t - 1)) * HID);
        float hv[16];
#pragma unroll
        for (int q = 0; q < 4; ++q) {
            float4 v = *(const float4*)(hp + l*16 + q*4);
            hv[q*4+0] = v.x; hv[q*4+1] = v.y; hv[q*4+2] = v.z; hv[q*4+3] = v.w;
        }

        float preval = 0.f;
        if (l < 8) preval = pre[(size_t)t*4096 + gate*HID + u0 + half*8 + l];

        float selz = 0.f;
#pragma unroll
        for (int r = 0; r < 8; ++r) {
            float acc = 0.f;
#pragma unroll
            for (int m = 0; m < 16; ++m) acc = fmaf(wreg[r][m], hv[m], acc);
            acc += __shfl_xor(acc, 32, 64);
            acc += __shfl_xor(acc, 16, 64);
            acc += __shfl_xor(acc,  8, 64);
            acc += __shfl_xor(acc,  4, 64);
            acc += __shfl_xor(acc,  2, 64);
            acc += __shfl_xor(acc,  1, 64);
            if (l == r) selz = acc;
        }

        __syncthreads();                                  // A: zbuf reusable
        if (l < 8) zbuf[gate*16 + half*8 + l] = selz + preval;
        __syncthreads();                                  // B: zbuf complete

        if (w2 == 0 && l < 16) {
            float zi = zbuf[l];
            float zf = zbuf[16 + l];
            float zg = zbuf[32 + l];
            float zo = zbuf[48 + l];
            float si = 1.f / (1.f + __expf(-zi));
            float sf = 1.f / (1.f + __expf(-zf));
            float tg = tanhf(zg);
            float so = 1.f / (1.f + __expf(-zo));
            creg = sf * creg + si * tg;
            float hn = so * tanhf(creg);
            hs[(size_t)t*HID + u0 + l] = hn;
        }
        if (tid == 0) {
            __hip_atomic_store(&myf[g], (unsigned)(s + 1), __ATOMIC_RELEASE,
                               __HIP_MEMORY_SCOPE_AGENT);
        }
    }
}

// ------------------------------------------------------------------ frames
// frames[t,j] = b_out[j] + sum_d hf[t,d]*Wout[d,j] + sum_d hb[t,d]*Wout[1024+d,j]
__global__ __launch_bounds__(256) void frames_kernel(
    const float* __restrict__ hs_f, const float* __restrict__ hs_b,
    const float* __restrict__ Wout, const float* __restrict__ bout,
    float* __restrict__ frames)
{
    const int tid = threadIdx.x;
    const int wv  = tid >> 6;
    const int l   = tid & 63;
    const int halft = l >> 5;
    const int j   = l & 31;
    const bool act = (j < NTAG);
    const int jj  = act ? j : 0;
    const int t   = blockIdx.x * 8 + wv * 2 + halft;

    const float* hf = hs_f + (size_t)t * HID;
    const float* hb = hs_b + (size_t)t * HID;
    float acc0 = 0.f, acc1 = 0.f;
#pragma unroll 4
    for (int dd = 0; dd < HID; ++dd)
        acc0 = fmaf(hf[dd], Wout[dd*NTAG + jj], acc0);
#pragma unroll 4
    for (int dd = 0; dd < HID; ++dd)
        acc1 = fmaf(hb[dd], Wout[(HID + dd)*NTAG + jj], acc1);
    if (act) frames[t*NTAG + j] = acc0 + acc1 + bout[j];
}

// ----------------------------------------------------------------- viterbi
// one wave. lane j<18 owns tag-column j. alpha kept as f32 differential d
// + f64 scalar base (renormalized each step). bps packed 6x5bit per u32 in LDS.
// Backtrace: per-lane 64-step map composition, then 63-step serial stitch.
__global__ __launch_bounds__(64, 1) void viterbi_kernel(
    const float* __restrict__ frames,
    const float* __restrict__ trans,
    float* __restrict__ out)
{
    const int l = threadIdx.x;           // 0..63
    const bool act = (l < NTAG);
    const int jj = act ? l : 0;

    __shared__ unsigned int bpsL[T_LEN * 3];
    __shared__ int MLDS[64][NTAG];
    __shared__ int ventry[64];

    float tcol[NTAG];
#pragma unroll
    for (int i = 0; i < NTAG; ++i) tcol[i] = trans[i*NTAG + jj];

    float d = act ? ((l == BEGIN_TAG) ? 0.f : NEGV) : -3.0e38f;
    double base = 0.0;

    float fcur = frames[jj];
    for (int t = 0; t < T_LEN; ++t) {
        float fnext = (t + 1 < T_LEN) ? frames[(size_t)(t + 1)*NTAG + jj] : 0.f;

        float m = -3.0e38f; int idx = 0;
        float v[NTAG];
#pragma unroll
        for (int i = 0; i < NTAG; ++i) {
            float ai = __shfl(d, i, 64);
            float vi = ai + tcol[i];
            v[i] = vi;
            if (vi > m) { m = vi; idx = i; }
        }
        float ssum = 0.f;
#pragma unroll
        for (int i = 0; i < NTAG; ++i) ssum += __expf(v[i] - m);
        float dn = act ? (fcur + m + __logf(ssum)) : -3.0e38f;

        // pack 18 x 5-bit backpointers into 3 words
        unsigned contrib = (unsigned)idx << (5 * (jj % 6));
        unsigned wword = 0;
#pragma unroll
        for (int q = 0; q < 6; ++q) {
            int srcl = (l < 3) ? (l*6 + q) : 0;
            wword |= __shfl(contrib, srcl, 64);
        }
        if (l < 3) bpsL[t*3 + l] = wword;

        // renormalize
        float mx = dn;
#pragma unroll
        for (int off = 32; off >= 1; off >>= 1)
            mx = fmaxf(mx, __shfl_xor(mx, off, 64));
        base += (double)mx;
        d = dn - mx;
        fcur = fnext;
    }

    // final scores
    float fin = act ? (d + trans[jj*NTAG + END_TAG]) : -3.0e38f;
    float m2 = -3.0e38f; int best = 0;
#pragma unroll
    for (int i = 0; i < NTAG; ++i) {
        float fv = __shfl(fin, i, 64);
        if (fv > m2) { m2 = fv; best = i; }
    }
    float s2 = 0.f;
#pragma unroll
    for (int i = 0; i < NTAG; ++i) {
        float fv = __shfl(fin, i, 64);
        s2 += __expf(fv - m2);
    }
    if (l == 0) out[0] = (float)(base + (double)m2 + (double)__logf(s2));

    __syncthreads();

    // per-lane chunk map composition: M = G_lo o ... o G_hi
    int M[NTAG];
#pragma unroll
    for (int x = 0; x < NTAG; ++x) M[x] = x;
    const int lo = l*64 + 1;
    const int hi = (l*64 + 64 < T_LEN) ? (l*64 + 64) : (T_LEN - 1);
    for (int t = hi; t >= lo; --t) {
#pragma unroll
        for (int x = 0; x < NTAG; ++x) {
            int vc = M[x];
            unsigned wv = bpsL[t*3 + (vc / 6)];
            M[x] = (int)((wv >> (5 * (vc % 6))) & 31u);
        }
    }
#pragma unroll
    for (int x = 0; x < NTAG; ++x) MLDS[l][x] = M[x];
    __syncthreads();

    if (l == 0) {
        int vc = best;
        ventry[63] = best;
        for (int c = 62; c >= 0; --c) { vc = MLDS[c + 1][vc]; ventry[c] = vc; }
    }
    __syncthreads();

    int x = ventry[l];
    if (l == 63) out[1 + T_LEN - 1] = (float)best;
    for (int t = hi; t >= lo; --t) {
        unsigned wv = bpsL[t*3 + (x / 6)];
        x = (int)((wv >> (5 * (x % 6))) & 31u);
        out[1 + t - 1] = (float)x;
    }
}

// ------------------------------------------------------------------ launch
extern "C" void kernel_launch(void* const* d_in, const int* in_sizes, int n_in,
                              void* d_out, int out_size, void* d_ws, size_t ws_size,
                              hipStream_t stream) {
    const int*   words = (const int*)  d_in[0];
    const float* h0    = (const float*)d_in[1];
    const float* c0    = (const float*)d_in[2];
    const float* emb   = (const float*)d_in[3];
    const float* Wih_f = (const float*)d_in[4];
    const float* Whh_f = (const float*)d_in[5];
    const float* b_f   = (const float*)d_in[6];
    const float* Wih_b = (const float*)d_in[7];
    const float* Whh_b = (const float*)d_in[8];
    const float* b_b   = (const float*)d_in[9];
    const float* Wout  = (const float*)d_in[10];
    const float* bout  = (const float*)d_in[11];
    const float* trans = (const float*)d_in[12];

    float* ws = (float*)d_ws;
    float* pre_f  = ws + OFF_PRE_F;
    float* pre_b  = ws + OFF_PRE_B;
    float* hs_f   = ws + OFF_HS_F;
    float* hs_b   = ws + OFF_HS_B;
    float* frames = ws + OFF_FRAMES;
    unsigned int* flags = (unsigned int*)(ws + OFF_FLAGS);
    float* out = (float*)d_out;

    hipLaunchKernelGGL(init_flags_kernel, dim3(1), dim3(128), 0, stream, flags);
    hipLaunchKernelGGL(pre_gemm_kernel, dim3(32, 32, 2), dim3(256), 0, stream,
                       words, emb, Wih_f, b_f, Wih_b, b_b, pre_f, pre_b);
    hipLaunchKernelGGL(rec_kernel, dim3(128), dim3(512), 0, stream,
                       Whh_f, Whh_b, pre_f, pre_b, h0, c0, hs_f, hs_b, flags);
    hipLaunchKernelGGL(frames_kernel, dim3(512), dim3(256), 0, stream,
                       hs_f, hs_b, Wout, bout, frames);
    hipLaunchKernelGGL(viterbi_kernel, dim3(1), dim3(64), 0, stream,
                       frames, trans, out);
}

// Round 2
// 24929.964 us; speedup vs baseline: 4.8668x; 4.8668x over previous
//
#include <hip/hip_runtime.h>
#include <hip/hip_bf16.h>

#define T_LEN 4096
#define HID   1024
#define NTAG  18
#define BEGIN_TAG 16
#define END_TAG   17
#define NEGV  -10000.0f

// workspace layout (float offsets)
#define OFF_PRE_F  0ull
#define OFF_PRE_B  16777216ull
#define OFF_HS_F   33554432ull
#define OFF_HS_B   37748736ull
#define OFF_FRAMES 41943040ull
#define OFF_FLAGS  42016768ull   // 128 x u32 lives here

// ---------------------------------------------------------------- init flags
__global__ void init_flags_kernel(unsigned int* flags) {
    if (threadIdx.x < 128) flags[threadIdx.x] = 0u;
}

// -------------------------------------------------- pre = emb[words] @ W_ih^T + b
// C[t,r] = sum_e emb[words[t],e] * W[r,e] + b[r];  M=4096 (t), N=4096 (r), K=512
// 128x128 tile, BK=32, 256 threads, 8x8 microtile.
__global__ __launch_bounds__(256) void pre_gemm_kernel(
    const int*   __restrict__ words,
    const float* __restrict__ emb,
    const float* __restrict__ Wf, const float* __restrict__ bf,
    const float* __restrict__ Wb, const float* __restrict__ bb,
    float* __restrict__ pre_f, float* __restrict__ pre_b)
{
    const int dir = blockIdx.z;
    const float* W    = dir ? Wb : Wf;
    const float* bias = dir ? bb : bf;
    float* pre        = dir ? pre_b : pre_f;
    const int tb = blockIdx.x * 128;
    const int nb = blockIdx.y * 128;
    const int tid = threadIdx.x;

    __shared__ float As[32][128];
    __shared__ float Bs[32][128];

    float acc[8][8];
#pragma unroll
    for (int i = 0; i < 8; ++i)
#pragma unroll
        for (int j = 0; j < 8; ++j) acc[i][j] = 0.f;

    const int row   = tid >> 1;           // 0..127
    const int ebase = (tid & 1) * 16;     // 0 / 16
    const int tm = tid >> 4;              // 0..15
    const int tn = tid & 15;              // 0..15

    const int wrow = words[tb + row];
    const float* aSrc = emb + (size_t)wrow * 512 + ebase;
    const float* bSrc = W   + (size_t)(nb + row) * 512 + ebase;

    for (int kk = 0; kk < 512; kk += 32) {
#pragma unroll
        for (int q = 0; q < 4; ++q) {
            float4 av = *(const float4*)(aSrc + kk + q * 4);
            float4 bv = *(const float4*)(bSrc + kk + q * 4);
            As[ebase + q*4 + 0][row] = av.x;
            As[ebase + q*4 + 1][row] = av.y;
            As[ebase + q*4 + 2][row] = av.z;
            As[ebase + q*4 + 3][row] = av.w;
            Bs[ebase + q*4 + 0][row] = bv.x;
            Bs[ebase + q*4 + 1][row] = bv.y;
            Bs[ebase + q*4 + 2][row] = bv.z;
            Bs[ebase + q*4 + 3][row] = bv.w;
        }
        __syncthreads();
#pragma unroll 4
        for (int k = 0; k < 32; ++k) {
            float a[8], b[8];
            *(float4*)&a[0] = *(const float4*)&As[k][tm*8];
            *(float4*)&a[4] = *(const float4*)&As[k][tm*8 + 4];
            *(float4*)&b[0] = *(const float4*)&Bs[k][tn*8];
            *(float4*)&b[4] = *(const float4*)&Bs[k][tn*8 + 4];
#pragma unroll
            for (int i = 0; i < 8; ++i)
#pragma unroll
                for (int j = 0; j < 8; ++j)
                    acc[i][j] = fmaf(a[i], b[j], acc[i][j]);
        }
        __syncthreads();
    }

    float bvals[8];
#pragma unroll
    for (int j = 0; j < 8; ++j) bvals[j] = bias[nb + tn*8 + j];

#pragma unroll
    for (int i = 0; i < 8; ++i) {
        const size_t r = (size_t)(tb + tm*8 + i);
        float o[8];
#pragma unroll
        for (int j = 0; j < 8; ++j) o[j] = acc[i][j] + bvals[j];
        *(float4*)(pre + r*4096 + nb + tn*8)     = *(float4*)&o[0];
        *(float4*)(pre + r*4096 + nb + tn*8 + 4) = *(float4*)&o[4];
    }
}

// -------------------------------------------------------------- recurrence
// 128 WGs: wg>>6 = direction, wg&63 = unit-group (16 hidden units).
// 512 threads = 8 waves: wave w2 owns units u0 + 2*w2 + {0,1}.
// Local row r (0..7): gate = r>>1, unit = unitbase + (r&1).
// Weights pinned in VGPRs via asm (prevents remat-into-loop; r1 showed VGPR=88
// i.e. the compiler reloaded W every step -> 400 GB fetch).
// Cross-WG protocol: ALL cross-WG data moves with RELAXED agent-scope atomics
// (sc0/sc1 accesses: stores write through to the coherence point, loads bypass
// possibly-stale L1/L2). No acquire/release -> no buffer_inv / buffer_wbl2 in
// the hot loop. Ordering: __syncthreads() drains each wave's vmcnt before the
// tid0 flag store; asm memory clobber stops hoisting of h loads above the poll.
__global__ __launch_bounds__(512, 2) void rec_kernel(
    const float* __restrict__ Whh_f, const float* __restrict__ Whh_b,
    const float* __restrict__ pre_f, const float* __restrict__ pre_b,
    const float* __restrict__ h0, const float* __restrict__ c0,
    float* __restrict__ hs_f, float* __restrict__ hs_b,
    unsigned int* __restrict__ flags)
{
    const int wg  = blockIdx.x;
    const int dir = wg >> 6;
    const int g   = wg & 63;
    const int u0  = g * 16;
    const int tid = threadIdx.x;
    const int w2  = tid >> 6;      // 0..7
    const int l   = tid & 63;
    const int unitbase = u0 + w2 * 2;

    const float* __restrict__ Whh = dir ? Whh_b : Whh_f;
    const float* __restrict__ pre = dir ? pre_b : pre_f;
    float* __restrict__ hs        = dir ? hs_b  : hs_f;
    unsigned int* __restrict__ myf = flags + dir * 64;

    float wreg[8][16];
#pragma unroll
    for (int r = 0; r < 8; ++r) {
        const int gate = r >> 1;
        const float* wr = Whh + (size_t)(gate * HID + unitbase + (r & 1)) * HID + l * 16;
#pragma unroll
        for (int q = 0; q < 4; ++q) {
            float4 v = *(const float4*)(wr + q * 4);
            wreg[r][q*4+0] = v.x; wreg[r][q*4+1] = v.y;
            wreg[r][q*4+2] = v.z; wreg[r][q*4+3] = v.w;
        }
    }
    // pin: asm results can't be rematerialized -> weights stay resident
#pragma unroll
    for (int r = 0; r < 8; ++r)
#pragma unroll
        for (int m = 0; m < 16; ++m)
            asm volatile("" : "+v"(wreg[r][m]));

    float creg = (l < 2) ? c0[dir * HID + unitbase + l] : 0.f;

    for (int s = 0; s < T_LEN; ++s) {
        const int t = dir ? (T_LEN - 1 - s) : s;

        if (s > 0) {
            while (true) {
                unsigned f = __hip_atomic_load(&myf[l], __ATOMIC_RELAXED,
                                               __HIP_MEMORY_SCOPE_AGENT);
                if (__all((int)(f >= (unsigned)s))) break;
                __builtin_amdgcn_s_sleep(1);
            }
        }
        asm volatile("" ::: "memory");   // keep h loads below the poll

        const float* hp = (s == 0) ? (h0 + dir * HID)
                                   : (hs + (size_t)(dir ? (t + 1) : (t - 1)) * HID);
        const unsigned long long* hq = (const unsigned long long*)hp + l * 8;
        float hv[16];
#pragma unroll
        for (int q = 0; q < 8; ++q) {
            unsigned long long uv = __hip_atomic_load(hq + q, __ATOMIC_RELAXED,
                                                      __HIP_MEMORY_SCOPE_AGENT);
            hv[2*q]   = __uint_as_float((unsigned)uv);
            hv[2*q+1] = __uint_as_float((unsigned)(uv >> 32));
        }

        float preval = 0.f;
        if (l < 8)
            preval = pre[(size_t)t * 4096 + (size_t)(l >> 1) * HID + unitbase + (l & 1)];

        float selz = 0.f;
#pragma unroll
        for (int r = 0; r < 8; ++r) {
            float acc = 0.f;
#pragma unroll
            for (int m = 0; m < 16; ++m) acc = fmaf(wreg[r][m], hv[m], acc);
            acc += __shfl_xor(acc, 32, 64);
            acc += __shfl_xor(acc, 16, 64);
            acc += __shfl_xor(acc,  8, 64);
            acc += __shfl_xor(acc,  4, 64);
            acc += __shfl_xor(acc,  2, 64);
            acc += __shfl_xor(acc,  1, 64);
            if (l == r) selz = acc;
        }
        float zrow = selz + preval;      // valid in lanes 0..7
        const int u = l & 1;
        float zi = __shfl(zrow, 0 + u, 64);
        float zf = __shfl(zrow, 2 + u, 64);
        float zg = __shfl(zrow, 4 + u, 64);
        float zo = __shfl(zrow, 6 + u, 64);
        float si = 1.f / (1.f + __expf(-zi));
        float sf = 1.f / (1.f + __expf(-zf));
        float tg = tanhf(zg);
        float so = 1.f / (1.f + __expf(-zo));
        float cn = sf * creg + si * tg;  // creg valid in lanes 0,1
        float hn = so * tanhf(cn);
        creg = cn;                        // only lanes 0,1 ever read back
        if (l < 2)
            __hip_atomic_store(&hs[(size_t)t * HID + unitbase + l], hn,
                               __ATOMIC_RELAXED, __HIP_MEMORY_SCOPE_AGENT);

        __syncthreads();   // each wave: s_waitcnt vmcnt(0) then barrier ->
                           // all 16 write-through stores are at L3 before...
        if (tid == 0)
            __hip_atomic_store(&myf[g], (unsigned)(s + 1), __ATOMIC_RELAXED,
                               __HIP_MEMORY_SCOPE_AGENT);
    }
}

// ------------------------------------------------------------------ frames
// frames[t,j] = b_out[j] + sum_d hf[t,d]*Wout[d,j] + sum_d hb[t,d]*Wout[1024+d,j]
__global__ __launch_bounds__(256) void frames_kernel(
    const float* __restrict__ hs_f, const float* __restrict__ hs_b,
    const float* __restrict__ Wout, const float* __restrict__ bout,
    float* __restrict__ frames)
{
    const int tid = threadIdx.x;
    const int wv  = tid >> 6;
    const int l   = tid & 63;
    const int halft = l >> 5;
    const int j   = l & 31;
    const bool act = (j < NTAG);
    const int jj  = act ? j : 0;
    const int t   = blockIdx.x * 8 + wv * 2 + halft;

    const float* hf = hs_f + (size_t)t * HID;
    const float* hb = hs_b + (size_t)t * HID;
    float acc0 = 0.f, acc1 = 0.f;
#pragma unroll 4
    for (int dd = 0; dd < HID; ++dd)
        acc0 = fmaf(hf[dd], Wout[dd*NTAG + jj], acc0);
#pragma unroll 4
    for (int dd = 0; dd < HID; ++dd)
        acc1 = fmaf(hb[dd], Wout[(HID + dd)*NTAG + jj], acc1);
    if (act) frames[t*NTAG + j] = acc0 + acc1 + bout[j];
}

// ----------------------------------------------------------------- viterbi
// one wave. lane j<18 owns tag-column j. alpha kept as f32 differential d
// + f64 scalar base (renormalized each step). bps packed 6x5bit per u32 in LDS.
// Backtrace: per-lane 64-step map composition, then 63-step serial stitch.
__global__ __launch_bounds__(64, 1) void viterbi_kernel(
    const float* __restrict__ frames,
    const float* __restrict__ trans,
    float* __restrict__ out)
{
    const int l = threadIdx.x;           // 0..63
    const bool act = (l < NTAG);
    const int jj = act ? l : 0;

    __shared__ unsigned int bpsL[T_LEN * 3];
    __shared__ int MLDS[64][NTAG];
    __shared__ int ventry[64];

    float tcol[NTAG];
#pragma unroll
    for (int i = 0; i < NTAG; ++i) tcol[i] = trans[i*NTAG + jj];

    float d = act ? ((l == BEGIN_TAG) ? 0.f : NEGV) : -3.0e38f;
    double base = 0.0;

    float fcur = frames[jj];
    for (int t = 0; t < T_LEN; ++t) {
        float fnext = (t + 1 < T_LEN) ? frames[(size_t)(t + 1)*NTAG + jj] : 0.f;

        float m = -3.0e38f; int idx = 0;
        float v[NTAG];
#pragma unroll
        for (int i = 0; i < NTAG; ++i) {
            float ai = __shfl(d, i, 64);
            float vi = ai + tcol[i];
            v[i] = vi;
            if (vi > m) { m = vi; idx = i; }
        }
        float ssum = 0.f;
#pragma unroll
        for (int i = 0; i < NTAG; ++i) ssum += __expf(v[i] - m);
        float dn = act ? (fcur + m + __logf(ssum)) : -3.0e38f;

        // pack 18 x 5-bit backpointers into 3 words
        unsigned contrib = (unsigned)idx << (5 * (jj % 6));
        unsigned wword = 0;
#pragma unroll
        for (int q = 0; q < 6; ++q) {
            int srcl = (l < 3) ? (l*6 + q) : 0;
            wword |= __shfl(contrib, srcl, 64);
        }
        if (l < 3) bpsL[t*3 + l] = wword;

        // renormalize
        float mx = dn;
#pragma unroll
        for (int off = 32; off >= 1; off >>= 1)
            mx = fmaxf(mx, __shfl_xor(mx, off, 64));
        base += (double)mx;
        d = dn - mx;
        fcur = fnext;
    }

    // final scores
    float fin = act ? (d + trans[jj*NTAG + END_TAG]) : -3.0e38f;
    float m2 = -3.0e38f; int best = 0;
#pragma unroll
    for (int i = 0; i < NTAG; ++i) {
        float fv = __shfl(fin, i, 64);
        if (fv > m2) { m2 = fv; best = i; }
    }
    float s2 = 0.f;
#pragma unroll
    for (int i = 0; i < NTAG; ++i) {
        float fv = __shfl(fin, i, 64);
        s2 += __expf(fv - m2);
    }
    if (l == 0) out[0] = (float)(base + (double)m2 + (double)__logf(s2));

    __syncthreads();

    // per-lane chunk map composition: M = G_lo o ... o G_hi
    int M[NTAG];
#pragma unroll
    for (int x = 0; x < NTAG; ++x) M[x] = x;
    const int lo = l*64 + 1;
    const int hi = (l*64 + 64 < T_LEN) ? (l*64 + 64) : (T_LEN - 1);
    for (int t = hi; t >= lo; --t) {
#pragma unroll
        for (int x = 0; x < NTAG; ++x) {
            int vc = M[x];
            unsigned wv = bpsL[t*3 + (vc / 6)];
            M[x] = (int)((wv >> (5 * (vc % 6))) & 31u);
        }
    }
#pragma unroll
    for (int x = 0; x < NTAG; ++x) MLDS[l][x] = M[x];
    __syncthreads();

    if (l == 0) {
        int vc = best;
        ventry[63] = best;
        for (int c = 62; c >= 0; --c) { vc = MLDS[c + 1][vc]; ventry[c] = vc; }
    }
    __syncthreads();

    int x = ventry[l];
    if (l == 63) out[1 + T_LEN - 1] = (float)best;
    for (int t = hi; t >= lo; --t) {
        unsigned wv = bpsL[t*3 + (x / 6)];
        x = (int)((wv >> (5 * (x % 6))) & 31u);
        out[1 + t - 1] = (float)x;
    }
}

// ------------------------------------------------------------------ launch
extern "C" void kernel_launch(void* const* d_in, const int* in_sizes, int n_in,
                              void* d_out, int out_size, void* d_ws, size_t ws_size,
                              hipStream_t stream) {
    const int*   words = (const int*)  d_in[0];
    const float* h0    = (const float*)d_in[1];
    const float* c0    = (const float*)d_in[2];
    const float* emb   = (const float*)d_in[3];
    const float* Wih_f = (const float*)d_in[4];
    const float* Whh_f = (const float*)d_in[5];
    const float* b_f   = (const float*)d_in[6];
    const float* Wih_b = (const float*)d_in[7];
    const float* Whh_b = (const float*)d_in[8];
    const float* b_b   = (const float*)d_in[9];
    const float* Wout  = (const float*)d_in[10];
    const float* bout  = (const float*)d_in[11];
    const float* trans = (const float*)d_in[12];

    float* ws = (float*)d_ws;
    float* pre_f  = ws + OFF_PRE_F;
    float* pre_b  = ws + OFF_PRE_B;
    float* hs_f   = ws + OFF_HS_F;
    float* hs_b   = ws + OFF_HS_B;
    float* frames = ws + OFF_FRAMES;
    unsigned int* flags = (unsigned int*)(ws + OFF_FLAGS);
    float* out = (float*)d_out;

    hipLaunchKernelGGL(init_flags_kernel, dim3(1), dim3(128), 0, stream, flags);
    hipLaunchKernelGGL(pre_gemm_kernel, dim3(32, 32, 2), dim3(256), 0, stream,
                       words, emb, Wih_f, b_f, Wih_b, b_b, pre_f, pre_b);
    hipLaunchKernelGGL(rec_kernel, dim3(128), dim3(512), 0, stream,
                       Whh_f, Whh_b, pre_f, pre_b, h0, c0, hs_f, hs_b, flags);
    hipLaunchKernelGGL(frames_kernel, dim3(512), dim3(256), 0, stream,
                       hs_f, hs_b, Wout, bout, frames);
    hipLaunchKernelGGL(viterbi_kernel, dim3(1), dim3(64), 0, stream,
                       frames, trans, out);
}

// Round 3
// 18814.824 us; speedup vs baseline: 6.4486x; 1.3250x over previous
//
#include <hip/hip_runtime.h>
#include <hip/hip_bf16.h>

#define T_LEN 4096
#define HID   1024
#define NTAG  18
#define BEGIN_TAG 16
#define END_TAG   17
#define NEGV  -10000.0f

// workspace layout (float offsets)
#define OFF_PRE_F  0ull
#define OFF_PRE_B  16777216ull
#define OFF_HS_F   33554432ull
#define OFF_HS_B   37748736ull
#define OFF_FRAMES 41943040ull
// flags (256 x u32) OVERLAP the frames region: flags are only live during
// rec_kernel; frames_kernel (which runs after rec completes) overwrites the
// whole region with real frame values. Keeps ws usage within the proven bound.

// ---------------------------------------------------------------- init flags
__global__ void init_flags_kernel(unsigned int* flags) {
    if (threadIdx.x < 256) flags[threadIdx.x] = 0u;
}

// -------------------------------------------------- pre = emb[words] @ W_ih^T + b
// C[t,r] = sum_e emb[words[t],e] * W[r,e] + b[r];  M=4096 (t), N=4096 (r), K=512
// 128x128 tile, BK=32, 256 threads, 8x8 microtile.
__global__ __launch_bounds__(256) void pre_gemm_kernel(
    const int*   __restrict__ words,
    const float* __restrict__ emb,
    const float* __restrict__ Wf, const float* __restrict__ bf,
    const float* __restrict__ Wb, const float* __restrict__ bb,
    float* __restrict__ pre_f, float* __restrict__ pre_b)
{
    const int dir = blockIdx.z;
    const float* W    = dir ? Wb : Wf;
    const float* bias = dir ? bb : bf;
    float* pre        = dir ? pre_b : pre_f;
    const int tb = blockIdx.x * 128;
    const int nb = blockIdx.y * 128;
    const int tid = threadIdx.x;

    __shared__ float As[32][128];
    __shared__ float Bs[32][128];

    float acc[8][8];
#pragma unroll
    for (int i = 0; i < 8; ++i)
#pragma unroll
        for (int j = 0; j < 8; ++j) acc[i][j] = 0.f;

    const int row   = tid >> 1;           // 0..127
    const int ebase = (tid & 1) * 16;     // 0 / 16
    const int tm = tid >> 4;              // 0..15
    const int tn = tid & 15;              // 0..15

    const int wrow = words[tb + row];
    const float* aSrc = emb + (size_t)wrow * 512 + ebase;
    const float* bSrc = W   + (size_t)(nb + row) * 512 + ebase;

    for (int kk = 0; kk < 512; kk += 32) {
#pragma unroll
        for (int q = 0; q < 4; ++q) {
            float4 av = *(const float4*)(aSrc + kk + q * 4);
            float4 bv = *(const float4*)(bSrc + kk + q * 4);
            As[ebase + q*4 + 0][row] = av.x;
            As[ebase + q*4 + 1][row] = av.y;
            As[ebase + q*4 + 2][row] = av.z;
            As[ebase + q*4 + 3][row] = av.w;
            Bs[ebase + q*4 + 0][row] = bv.x;
            Bs[ebase + q*4 + 1][row] = bv.y;
            Bs[ebase + q*4 + 2][row] = bv.z;
            Bs[ebase + q*4 + 3][row] = bv.w;
        }
        __syncthreads();
#pragma unroll 4
        for (int k = 0; k < 32; ++k) {
            float a[8], b[8];
            *(float4*)&a[0] = *(const float4*)&As[k][tm*8];
            *(float4*)&a[4] = *(const float4*)&As[k][tm*8 + 4];
            *(float4*)&b[0] = *(const float4*)&Bs[k][tn*8];
            *(float4*)&b[4] = *(const float4*)&Bs[k][tn*8 + 4];
#pragma unroll
            for (int i = 0; i < 8; ++i)
#pragma unroll
                for (int j = 0; j < 8; ++j)
                    acc[i][j] = fmaf(a[i], b[j], acc[i][j]);
        }
        __syncthreads();
    }

    float bvals[8];
#pragma unroll
    for (int j = 0; j < 8; ++j) bvals[j] = bias[nb + tn*8 + j];

#pragma unroll
    for (int i = 0; i < 8; ++i) {
        const size_t r = (size_t)(tb + tm*8 + i);
        float o[8];
#pragma unroll
        for (int j = 0; j < 8; ++j) o[j] = acc[i][j] + bvals[j];
        *(float4*)(pre + r*4096 + nb + tn*8)     = *(float4*)&o[0];
        *(float4*)(pre + r*4096 + nb + tn*8 + 4) = *(float4*)&o[4];
    }
}

// -------------------------------------------------------------- recurrence
// 256 WGs (1/CU): dir = wg>>7, g = wg&127, units u0 = g*8 .. g*8+7.
// 512 threads = 8 waves; wave w2 owns unit u = g*8 + w2 (its 4 gate rows).
// Lane l covers k in {q*256 + l*4 + j} -> wreg[4][16] = 64 VGPRs (fits; r2's
// wreg[8][16]=128 spilled to scratch -> VGPR_Count=88 + scratch storm).
// Wave 0 alone polls the 128 flags and stages the 4KB h vector into LDS
// (8x less poll + h L3 traffic than all-wave); stage barrier releases waves.
// All cross-WG data relaxed agent-scope (no buffer_inv in loop); ordering by
// __syncthreads vmcnt-drain before the tid0 flag store (proven in r2).
__global__ __launch_bounds__(512)
__attribute__((amdgpu_waves_per_eu(2, 2)))
void rec_kernel(
    const float* __restrict__ Whh_f, const float* __restrict__ Whh_b,
    const float* __restrict__ pre_f, const float* __restrict__ pre_b,
    const float* __restrict__ h0, const float* __restrict__ c0,
    float* __restrict__ hs_f, float* __restrict__ hs_b,
    unsigned int* __restrict__ flags)
{
    const int wg  = blockIdx.x;
    const int dir = wg >> 7;
    const int g   = wg & 127;
    const int tid = threadIdx.x;
    const int w2  = tid >> 6;      // 0..7
    const int l   = tid & 63;
    const int u   = g * 8 + w2;    // this wave's hidden unit

    const float* __restrict__ Whh = dir ? Whh_b : Whh_f;
    const float* __restrict__ pre = dir ? pre_b : pre_f;
    float* __restrict__ hs        = dir ? hs_b  : hs_f;
    unsigned int* __restrict__ myf = flags + dir * 128;

    // wreg[gate][m]: W_hh[gate*HID+u][q*256 + l*4 + j], m = q*4+j
    float wreg[4][16];
#pragma unroll
    for (int g4 = 0; g4 < 4; ++g4) {
        const float* wr = Whh + (size_t)(g4 * HID + u) * HID + l * 4;
#pragma unroll
        for (int q = 0; q < 4; ++q) {
            float4 v = *(const float4*)(wr + q * 256);
            wreg[g4][q*4+0] = v.x; wreg[g4][q*4+1] = v.y;
            wreg[g4][q*4+2] = v.z; wreg[g4][q*4+3] = v.w;
        }
    }
#pragma unroll
    for (int g4 = 0; g4 < 4; ++g4)
#pragma unroll
        for (int m = 0; m < 16; ++m)
            asm volatile("" : "+v"(wreg[g4][m]));

    float creg = c0[dir * HID + u];     // broadcast; all lanes identical

    __shared__ __align__(16) float hbuf[HID];

    const int tstep = dir ? -1 : 1;
    int t = dir ? (T_LEN - 1) : 0;

    // software-pipelined pre load (pre is cold HBM; hide it one step ahead)
    float preval = (l < 4) ? pre[(size_t)t * 4096 + (size_t)l * HID + u] : 0.f;

    for (int s = 0; s < T_LEN; ++s, t += tstep) {
        if (w2 == 0) {
            if (s > 0) {
                const unsigned long long* fq =
                    (const unsigned long long*)myf + l;   // flags[2l], [2l+1]
                while (true) {
                    unsigned long long f2 = __hip_atomic_load(
                        fq, __ATOMIC_RELAXED, __HIP_MEMORY_SCOPE_AGENT);
                    bool ok = ((unsigned)f2 >= (unsigned)s) &&
                              ((unsigned)(f2 >> 32) >= (unsigned)s);
                    if (__all(ok)) break;
                    __builtin_amdgcn_s_sleep(1);
                }
                asm volatile("" ::: "memory");  // keep h loads below the poll
            }
            const float* hp = (s == 0) ? (h0 + dir * HID)
                                       : (hs + (size_t)(t - tstep) * HID);
            const unsigned long long* hq = (const unsigned long long*)hp;
            unsigned long long hst[8];
#pragma unroll
            for (int q = 0; q < 8; ++q)
                hst[q] = __hip_atomic_load(hq + q * 64 + l, __ATOMIC_RELAXED,
                                           __HIP_MEMORY_SCOPE_AGENT);
            unsigned long long* hb = (unsigned long long*)hbuf;
#pragma unroll
            for (int q = 0; q < 8; ++q)
                hb[q * 64 + l] = hst[q];
        }
        __syncthreads();   // releases waves 1..7; lgkm-drains wave0's ds_write

        float hv[16];
#pragma unroll
        for (int q = 0; q < 4; ++q) {
            float4 v = *(const float4*)&hbuf[q * 256 + l * 4];
            hv[q*4+0] = v.x; hv[q*4+1] = v.y; hv[q*4+2] = v.z; hv[q*4+3] = v.w;
        }

        // prefetch next step's pre (use is one iteration away)
        float preval_next = 0.f;
        if (l < 4 && s + 1 < T_LEN)
            preval_next = pre[(size_t)(t + tstep) * 4096 + (size_t)l * HID + u];

        float z[4];
#pragma unroll
        for (int g4 = 0; g4 < 4; ++g4) {
            float acc = 0.f;
#pragma unroll
            for (int m = 0; m < 16; ++m) acc = fmaf(wreg[g4][m], hv[m], acc);
            acc += __shfl_xor(acc, 32, 64);
            acc += __shfl_xor(acc, 16, 64);
            acc += __shfl_xor(acc,  8, 64);
            acc += __shfl_xor(acc,  4, 64);
            acc += __shfl_xor(acc,  2, 64);
            acc += __shfl_xor(acc,  1, 64);
            z[g4] = acc + __shfl(preval, g4, 64);
        }
        float si = 1.f / (1.f + __expf(-z[0]));
        float sf = 1.f / (1.f + __expf(-z[1]));
        float tg = tanhf(z[2]);
        float so = 1.f / (1.f + __expf(-z[3]));
        float cn = sf * creg + si * tg;
        float hn = so * tanhf(cn);
        creg = cn;
        if (l == 0)
            __hip_atomic_store(&hs[(size_t)t * HID + u], hn,
                               __ATOMIC_RELAXED, __HIP_MEMORY_SCOPE_AGENT);

        __syncthreads();   // each wave vmcnt(0)-drains its h store first
        if (tid == 0)
            __hip_atomic_store(&myf[g], (unsigned)(s + 1),
                               __ATOMIC_RELAXED, __HIP_MEMORY_SCOPE_AGENT);
        preval = preval_next;
    }
}

// ------------------------------------------------------------------ frames
// frames[t,j] = b_out[j] + sum_d hf[t,d]*Wout[d,j] + sum_d hb[t,d]*Wout[1024+d,j]
__global__ __launch_bounds__(256) void frames_kernel(
    const float* __restrict__ hs_f, const float* __restrict__ hs_b,
    const float* __restrict__ Wout, const float* __restrict__ bout,
    float* __restrict__ frames)
{
    const int tid = threadIdx.x;
    const int wv  = tid >> 6;
    const int l   = tid & 63;
    const int halft = l >> 5;
    const int j   = l & 31;
    const bool act = (j < NTAG);
    const int jj  = act ? j : 0;
    const int t   = blockIdx.x * 8 + wv * 2 + halft;

    const float* hf = hs_f + (size_t)t * HID;
    const float* hb = hs_b + (size_t)t * HID;
    float acc0 = 0.f, acc1 = 0.f;
#pragma unroll 4
    for (int dd = 0; dd < HID; ++dd)
        acc0 = fmaf(hf[dd], Wout[dd*NTAG + jj], acc0);
#pragma unroll 4
    for (int dd = 0; dd < HID; ++dd)
        acc1 = fmaf(hb[dd], Wout[(HID + dd)*NTAG + jj], acc1);
    if (act) frames[t*NTAG + j] = acc0 + acc1 + bout[j];
}

// ----------------------------------------------------------------- viterbi
// one wave. lane j<18 owns tag-column j. alpha kept as f32 differential d
// + f64 scalar base (renormalized each step). bps packed 6x5bit per u32 in LDS.
// Backtrace: per-lane 64-step map composition, then 63-step serial stitch.
__global__ __launch_bounds__(64, 1) void viterbi_kernel(
    const float* __restrict__ frames,
    const float* __restrict__ trans,
    float* __restrict__ out)
{
    const int l = threadIdx.x;           // 0..63
    const bool act = (l < NTAG);
    const int jj = act ? l : 0;

    __shared__ unsigned int bpsL[T_LEN * 3];
    __shared__ int MLDS[64][NTAG];
    __shared__ int ventry[64];

    float tcol[NTAG];
#pragma unroll
    for (int i = 0; i < NTAG; ++i) tcol[i] = trans[i*NTAG + jj];

    float d = act ? ((l == BEGIN_TAG) ? 0.f : NEGV) : -3.0e38f;
    double base = 0.0;

    float fcur = frames[jj];
    for (int t = 0; t < T_LEN; ++t) {
        float fnext = (t + 1 < T_LEN) ? frames[(size_t)(t + 1)*NTAG + jj] : 0.f;

        float m = -3.0e38f; int idx = 0;
        float v[NTAG];
#pragma unroll
        for (int i = 0; i < NTAG; ++i) {
            float ai = __shfl(d, i, 64);
            float vi = ai + tcol[i];
            v[i] = vi;
            if (vi > m) { m = vi; idx = i; }
        }
        float ssum = 0.f;
#pragma unroll
        for (int i = 0; i < NTAG; ++i) ssum += __expf(v[i] - m);
        float dn = act ? (fcur + m + __logf(ssum)) : -3.0e38f;

        // pack 18 x 5-bit backpointers into 3 words
        unsigned contrib = (unsigned)idx << (5 * (jj % 6));
        unsigned wword = 0;
#pragma unroll
        for (int q = 0; q < 6; ++q) {
            int srcl = (l < 3) ? (l*6 + q) : 0;
            wword |= __shfl(contrib, srcl, 64);
        }
        if (l < 3) bpsL[t*3 + l] = wword;

        // renormalize
        float mx = dn;
#pragma unroll
        for (int off = 32; off >= 1; off >>= 1)
            mx = fmaxf(mx, __shfl_xor(mx, off, 64));
        base += (double)mx;
        d = dn - mx;
        fcur = fnext;
    }

    // final scores
    float fin = act ? (d + trans[jj*NTAG + END_TAG]) : -3.0e38f;
    float m2 = -3.0e38f; int best = 0;
#pragma unroll
    for (int i = 0; i < NTAG; ++i) {
        float fv = __shfl(fin, i, 64);
        if (fv > m2) { m2 = fv; best = i; }
    }
    float s2 = 0.f;
#pragma unroll
    for (int i = 0; i < NTAG; ++i) {
        float fv = __shfl(fin, i, 64);
        s2 += __expf(fv - m2);
    }
    if (l == 0) out[0] = (float)(base + (double)m2 + (double)__logf(s2));

    __syncthreads();

    // per-lane chunk map composition: M = G_lo o ... o G_hi
    int M[NTAG];
#pragma unroll
    for (int x = 0; x < NTAG; ++x) M[x] = x;
    const int lo = l*64 + 1;
    const int hi = (l*64 + 64 < T_LEN) ? (l*64 + 64) : (T_LEN - 1);
    for (int t = hi; t >= lo; --t) {
#pragma unroll
        for (int x = 0; x < NTAG; ++x) {
            int vc = M[x];
            unsigned wv = bpsL[t*3 + (vc / 6)];
            M[x] = (int)((wv >> (5 * (vc % 6))) & 31u);
        }
    }
#pragma unroll
    for (int x = 0; x < NTAG; ++x) MLDS[l][x] = M[x];
    __syncthreads();

    if (l == 0) {
        int vc = best;
        ventry[63] = best;
        for (int c = 62; c >= 0; --c) { vc = MLDS[c + 1][vc]; ventry[c] = vc; }
    }
    __syncthreads();

    int x = ventry[l];
    if (l == 63) out[1 + T_LEN - 1] = (float)best;
    for (int t = hi; t >= lo; --t) {
        unsigned wv = bpsL[t*3 + (x / 6)];
        x = (int)((wv >> (5 * (x % 6))) & 31u);
        out[1 + t - 1] = (float)x;
    }
}

// ------------------------------------------------------------------ launch
extern "C" void kernel_launch(void* const* d_in, const int* in_sizes, int n_in,
                              void* d_out, int out_size, void* d_ws, size_t ws_size,
                              hipStream_t stream) {
    const int*   words = (const int*)  d_in[0];
    const float* h0    = (const float*)d_in[1];
    const float* c0    = (const float*)d_in[2];
    const float* emb   = (const float*)d_in[3];
    const float* Wih_f = (const float*)d_in[4];
    const float* Whh_f = (const float*)d_in[5];
    const float* b_f   = (const float*)d_in[6];
    const float* Wih_b = (const float*)d_in[7];
    const float* Whh_b = (const float*)d_in[8];
    const float* b_b   = (const float*)d_in[9];
    const float* Wout  = (const float*)d_in[10];
    const float* bout  = (const float*)d_in[11];
    const float* trans = (const float*)d_in[12];

    float* ws = (float*)d_ws;
    float* pre_f  = ws + OFF_PRE_F;
    float* pre_b  = ws + OFF_PRE_B;
    float* hs_f   = ws + OFF_HS_F;
    float* hs_b   = ws + OFF_HS_B;
    float* frames = ws + OFF_FRAMES;
    unsigned int* flags = (unsigned int*)(ws + OFF_FRAMES);  // dead before frames written
    float* out = (float*)d_out;

    hipLaunchKernelGGL(init_flags_kernel, dim3(1), dim3(256), 0, stream, flags);
    hipLaunchKernelGGL(pre_gemm_kernel, dim3(32, 32, 2), dim3(256), 0, stream,
                       words, emb, Wih_f, b_f, Wih_b, b_b, pre_f, pre_b);
    hipLaunchKernelGGL(rec_kernel, dim3(256), dim3(512), 0, stream,
                       Whh_f, Whh_b, pre_f, pre_b, h0, c0, hs_f, hs_b, flags);
    hipLaunchKernelGGL(frames_kernel, dim3(512), dim3(256), 0, stream,
                       hs_f, hs_b, Wout, bout, frames);
    hipLaunchKernelGGL(viterbi_kernel, dim3(1), dim3(64), 0, stream,
                       frames, trans, out);
}

// Round 4
// 13485.199 us; speedup vs baseline: 8.9972x; 1.3952x over previous
//
#include <hip/hip_runtime.h>
#include <hip/hip_bf16.h>

#define T_LEN 4096
#define HID   1024
#define NTAG  18
#define BEGIN_TAG 16
#define END_TAG   17
#define NEGV  -10000.0f

// workspace layout (float offsets)
#define OFF_PRE_F  0ull
#define OFF_PRE_B  16777216ull
#define OFF_HS_F   33554432ull
#define OFF_HS_B   37748736ull
#define OFF_FRAMES 41943040ull
// mailbox (2 dir x 2 slot x 1024 units x u64 = 32 KB) OVERLAPS the frames
// region: it is only live during rec_kernel; frames_kernel overwrites it.

// ---------------------------------------------------------------- init mbox
__global__ void init_mbox_kernel(unsigned long long* mbox) {
    mbox[blockIdx.x * 1024 + threadIdx.x] = 0ull;   // grid 4 x block 1024
}

// -------------------------------------------------- pre = emb[words] @ W_ih^T + b
// C[t,r] = sum_e emb[words[t],e] * W[r,e] + b[r];  M=4096 (t), N=4096 (r), K=512
// 128x128 tile, BK=32, 256 threads, 8x8 microtile.
__global__ __launch_bounds__(256) void pre_gemm_kernel(
    const int*   __restrict__ words,
    const float* __restrict__ emb,
    const float* __restrict__ Wf, const float* __restrict__ bf,
    const float* __restrict__ Wb, const float* __restrict__ bb,
    float* __restrict__ pre_f, float* __restrict__ pre_b)
{
    const int dir = blockIdx.z;
    const float* W    = dir ? Wb : Wf;
    const float* bias = dir ? bb : bf;
    float* pre        = dir ? pre_b : pre_f;
    const int tb = blockIdx.x * 128;
    const int nb = blockIdx.y * 128;
    const int tid = threadIdx.x;

    __shared__ float As[32][128];
    __shared__ float Bs[32][128];

    float acc[8][8];
#pragma unroll
    for (int i = 0; i < 8; ++i)
#pragma unroll
        for (int j = 0; j < 8; ++j) acc[i][j] = 0.f;

    const int row   = tid >> 1;           // 0..127
    const int ebase = (tid & 1) * 16;     // 0 / 16
    const int tm = tid >> 4;              // 0..15
    const int tn = tid & 15;              // 0..15

    const int wrow = words[tb + row];
    const float* aSrc = emb + (size_t)wrow * 512 + ebase;
    const float* bSrc = W   + (size_t)(nb + row) * 512 + ebase;

    for (int kk = 0; kk < 512; kk += 32) {
#pragma unroll
        for (int q = 0; q < 4; ++q) {
            float4 av = *(const float4*)(aSrc + kk + q * 4);
            float4 bv = *(const float4*)(bSrc + kk + q * 4);
            As[ebase + q*4 + 0][row] = av.x;
            As[ebase + q*4 + 1][row] = av.y;
            As[ebase + q*4 + 2][row] = av.z;
            As[ebase + q*4 + 3][row] = av.w;
            Bs[ebase + q*4 + 0][row] = bv.x;
            Bs[ebase + q*4 + 1][row] = bv.y;
            Bs[ebase + q*4 + 2][row] = bv.z;
            Bs[ebase + q*4 + 3][row] = bv.w;
        }
        __syncthreads();
#pragma unroll 4
        for (int k = 0; k < 32; ++k) {
            float a[8], b[8];
            *(float4*)&a[0] = *(const float4*)&As[k][tm*8];
            *(float4*)&a[4] = *(const float4*)&As[k][tm*8 + 4];
            *(float4*)&b[0] = *(const float4*)&Bs[k][tn*8];
            *(float4*)&b[4] = *(const float4*)&Bs[k][tn*8 + 4];
#pragma unroll
            for (int i = 0; i < 8; ++i)
#pragma unroll
                for (int j = 0; j < 8; ++j)
                    acc[i][j] = fmaf(a[i], b[j], acc[i][j]);
        }
        __syncthreads();
    }

    float bvals[8];
#pragma unroll
    for (int j = 0; j < 8; ++j) bvals[j] = bias[nb + tn*8 + j];

#pragma unroll
    for (int i = 0; i < 8; ++i) {
        const size_t r = (size_t)(tb + tm*8 + i);
        float o[8];
#pragma unroll
        for (int j = 0; j < 8; ++j) o[j] = acc[i][j] + bvals[j];
        *(float4*)(pre + r*4096 + nb + tn*8)     = *(float4*)&o[0];
        *(float4*)(pre + r*4096 + nb + tn*8 + 4) = *(float4*)&o[4];
    }
}

// -------------------------------------------------------------- recurrence
// 256 WGs (1/CU): dir = wg>>7, g = wg&127, wave w2 owns unit u = g*8 + w2.
// Seq-tagged mailbox protocol: producer packs {f32 h, u32 tag=s+1} in ONE u64
// relaxed agent-scope store to mbox[dir][s&1][u] (fire-and-forget: the tag IS
// the flag, same 8B => no vmcnt drain, no separate flag, no trailing barrier).
// Consumers: wave w2 polls its 128-unit slice (2 u64/lane = one 16B pair) of
// slot (s-1)&1 until all tags >= s; the successful poll loads ARE the h data.
// Depth-2 ping-pong is race-free: a producer reaches step s+1 only after ALL
// waves completed step s (its step-s+1 poll needs every tag s+1), and a wave
// that passed its poll already holds the data in registers.
// LDS h buffer double-buffered => single __syncthreads per step.
__global__ __launch_bounds__(512)
__attribute__((amdgpu_waves_per_eu(2, 2)))
void rec_kernel(
    const float* __restrict__ Whh_f, const float* __restrict__ Whh_b,
    const float* __restrict__ pre_f, const float* __restrict__ pre_b,
    const float* __restrict__ h0, const float* __restrict__ c0,
    float* __restrict__ hs_f, float* __restrict__ hs_b,
    unsigned long long* __restrict__ mbox)
{
    const int wg  = blockIdx.x;
    const int dir = wg >> 7;
    const int g   = wg & 127;
    const int tid = threadIdx.x;
    const int w2  = tid >> 6;      // 0..7
    const int l   = tid & 63;
    const int u   = g * 8 + w2;    // this wave's hidden unit

    const float* __restrict__ Whh = dir ? Whh_b : Whh_f;
    const float* __restrict__ pre = dir ? pre_b : pre_f;
    float* __restrict__ hs        = dir ? hs_b  : hs_f;
    unsigned long long* __restrict__ mb = mbox + dir * 2048;  // [slot][unit]

    // wreg[gate][m]: W_hh[gate*HID+u][q*256 + l*4 + j], m = q*4+j
    float wreg[4][16];
#pragma unroll
    for (int g4 = 0; g4 < 4; ++g4) {
        const float* wr = Whh + (size_t)(g4 * HID + u) * HID + l * 4;
#pragma unroll
        for (int q = 0; q < 4; ++q) {
            float4 v = *(const float4*)(wr + q * 256);
            wreg[g4][q*4+0] = v.x; wreg[g4][q*4+1] = v.y;
            wreg[g4][q*4+2] = v.z; wreg[g4][q*4+3] = v.w;
        }
    }
#pragma unroll
    for (int g4 = 0; g4 < 4; ++g4)
#pragma unroll
        for (int m = 0; m < 16; ++m)
            asm volatile("" : "+v"(wreg[g4][m]));

    float creg = c0[dir * HID + u];     // broadcast; all lanes identical

    __shared__ __align__(16) float hbuf[2][HID];

    const int tstep = dir ? -1 : 1;
    int t = dir ? (T_LEN - 1) : 0;

    // software-pipelined pre load (pre is cold; hide it one step ahead)
    float preval = (l < 4) ? pre[(size_t)t * 4096 + (size_t)l * HID + u] : 0.f;

    const int slice = w2 * 128 + 2 * l;   // this lane's 2 polled units

    for (int s = 0; s < T_LEN; ++s, t += tstep) {
        float f0, f1;
        if (s == 0) {
            f0 = h0[dir * HID + slice];
            f1 = h0[dir * HID + slice + 1];
        } else {
            const unsigned long long* mp = mb + ((s - 1) & 1) * 1024 + slice;
            unsigned long long a, b;
            while (true) {
                a = __hip_atomic_load(mp,     __ATOMIC_RELAXED,
                                      __HIP_MEMORY_SCOPE_AGENT);
                b = __hip_atomic_load(mp + 1, __ATOMIC_RELAXED,
                                      __HIP_MEMORY_SCOPE_AGENT);
                bool ok = ((unsigned)(a >> 32) >= (unsigned)s) &&
                          ((unsigned)(b >> 32) >= (unsigned)s);
                if (__all(ok)) break;
                __builtin_amdgcn_s_sleep(2);
            }
            f0 = __uint_as_float((unsigned)a);
            f1 = __uint_as_float((unsigned)b);
        }
        // stage this wave's slice into the double-buffered LDS h
        float2* dst = (float2*)&hbuf[s & 1][slice];
        *dst = make_float2(f0, f1);
        __syncthreads();   // all slices staged; also WAR-protects buf[s&1]
                           // against step s-2 readers (one barrier suffices
                           // with double buffering)

        float hv[16];
#pragma unroll
        for (int q = 0; q < 4; ++q) {
            float4 v = *(const float4*)&hbuf[s & 1][q * 256 + l * 4];
            hv[q*4+0] = v.x; hv[q*4+1] = v.y; hv[q*4+2] = v.z; hv[q*4+3] = v.w;
        }

        // prefetch next step's pre (use is one iteration away)
        float preval_next = 0.f;
        if (l < 4 && s + 1 < T_LEN)
            preval_next = pre[(size_t)(t + tstep) * 4096 + (size_t)l * HID + u];

        float z[4];
#pragma unroll
        for (int g4 = 0; g4 < 4; ++g4) {
            float acc = 0.f;
#pragma unroll
            for (int m = 0; m < 16; ++m) acc = fmaf(wreg[g4][m], hv[m], acc);
            acc += __shfl_xor(acc, 32, 64);
            acc += __shfl_xor(acc, 16, 64);
            acc += __shfl_xor(acc,  8, 64);
            acc += __shfl_xor(acc,  4, 64);
            acc += __shfl_xor(acc,  2, 64);
            acc += __shfl_xor(acc,  1, 64);
            z[g4] = acc + __shfl(preval, g4, 64);
        }
        float si = 1.f / (1.f + __expf(-z[0]));
        float sf = 1.f / (1.f + __expf(-z[1]));
        float tg = tanhf(z[2]);
        float so = 1.f / (1.f + __expf(-z[3]));
        float cn = sf * creg + si * tg;
        float hn = so * tanhf(cn);
        creg = cn;
        if (l == 0) {
            hs[(size_t)t * HID + u] = hn;    // history for frames (off path)
            unsigned long long pk =
                ((unsigned long long)(unsigned)(s + 1) << 32) |
                (unsigned long long)__float_as_uint(hn);
            __hip_atomic_store(&mb[(s & 1) * 1024 + u], pk,
                               __ATOMIC_RELAXED, __HIP_MEMORY_SCOPE_AGENT);
        }
        preval = preval_next;
        // no trailing barrier: mailbox tag carries the ordering
    }
}

// ------------------------------------------------------------------ frames
// frames[t,j] = b_out[j] + sum_d hf[t,d]*Wout[d,j] + sum_d hb[t,d]*Wout[1024+d,j]
__global__ __launch_bounds__(256) void frames_kernel(
    const float* __restrict__ hs_f, const float* __restrict__ hs_b,
    const float* __restrict__ Wout, const float* __restrict__ bout,
    float* __restrict__ frames)
{
    const int tid = threadIdx.x;
    const int wv  = tid >> 6;
    const int l   = tid & 63;
    const int halft = l >> 5;
    const int j   = l & 31;
    const bool act = (j < NTAG);
    const int jj  = act ? j : 0;
    const int t   = blockIdx.x * 8 + wv * 2 + halft;

    const float* hf = hs_f + (size_t)t * HID;
    const float* hb = hs_b + (size_t)t * HID;
    float acc0 = 0.f, acc1 = 0.f;
#pragma unroll 4
    for (int dd = 0; dd < HID; ++dd)
        acc0 = fmaf(hf[dd], Wout[dd*NTAG + jj], acc0);
#pragma unroll 4
    for (int dd = 0; dd < HID; ++dd)
        acc1 = fmaf(hb[dd], Wout[(HID + dd)*NTAG + jj], acc1);
    if (act) frames[t*NTAG + j] = acc0 + acc1 + bout[j];
}

// ----------------------------------------------------------------- viterbi
// one wave. lane j<18 owns tag-column j. alpha kept as f32 differential d
// + f64 scalar base (renormalized each step). bps packed 6x5bit per u32 in LDS.
// Backtrace: per-lane 64-step map composition, then 63-step serial stitch.
__global__ __launch_bounds__(64, 1) void viterbi_kernel(
    const float* __restrict__ frames,
    const float* __restrict__ trans,
    float* __restrict__ out)
{
    const int l = threadIdx.x;           // 0..63
    const bool act = (l < NTAG);
    const int jj = act ? l : 0;

    __shared__ unsigned int bpsL[T_LEN * 3];
    __shared__ int MLDS[64][NTAG];
    __shared__ int ventry[64];

    float tcol[NTAG];
#pragma unroll
    for (int i = 0; i < NTAG; ++i) tcol[i] = trans[i*NTAG + jj];

    float d = act ? ((l == BEGIN_TAG) ? 0.f : NEGV) : -3.0e38f;
    double base = 0.0;

    float fcur = frames[jj];
    for (int t = 0; t < T_LEN; ++t) {
        float fnext = (t + 1 < T_LEN) ? frames[(size_t)(t + 1)*NTAG + jj] : 0.f;

        float m = -3.0e38f; int idx = 0;
        float v[NTAG];
#pragma unroll
        for (int i = 0; i < NTAG; ++i) {
            float ai = __shfl(d, i, 64);
            float vi = ai + tcol[i];
            v[i] = vi;
            if (vi > m) { m = vi; idx = i; }
        }
        float ssum = 0.f;
#pragma unroll
        for (int i = 0; i < NTAG; ++i) ssum += __expf(v[i] - m);
        float dn = act ? (fcur + m + __logf(ssum)) : -3.0e38f;

        // pack 18 x 5-bit backpointers into 3 words
        unsigned contrib = (unsigned)idx << (5 * (jj % 6));
        unsigned wword = 0;
#pragma unroll
        for (int q = 0; q < 6; ++q) {
            int srcl = (l < 3) ? (l*6 + q) : 0;
            wword |= __shfl(contrib, srcl, 64);
        }
        if (l < 3) bpsL[t*3 + l] = wword;

        // renormalize
        float mx = dn;
#pragma unroll
        for (int off = 32; off >= 1; off >>= 1)
            mx = fmaxf(mx, __shfl_xor(mx, off, 64));
        base += (double)mx;
        d = dn - mx;
        fcur = fnext;
    }

    // final scores
    float fin = act ? (d + trans[jj*NTAG + END_TAG]) : -3.0e38f;
    float m2 = -3.0e38f; int best = 0;
#pragma unroll
    for (int i = 0; i < NTAG; ++i) {
        float fv = __shfl(fin, i, 64);
        if (fv > m2) { m2 = fv; best = i; }
    }
    float s2 = 0.f;
#pragma unroll
    for (int i = 0; i < NTAG; ++i) {
        float fv = __shfl(fin, i, 64);
        s2 += __expf(fv - m2);
    }
    if (l == 0) out[0] = (float)(base + (double)m2 + (double)__logf(s2));

    __syncthreads();

    // per-lane chunk map composition: M = G_lo o ... o G_hi
    int M[NTAG];
#pragma unroll
    for (int x = 0; x < NTAG; ++x) M[x] = x;
    const int lo = l*64 + 1;
    const int hi = (l*64 + 64 < T_LEN) ? (l*64 + 64) : (T_LEN - 1);
    for (int t = hi; t >= lo; --t) {
#pragma unroll
        for (int x = 0; x < NTAG; ++x) {
            int vc = M[x];
            unsigned wv = bpsL[t*3 + (vc / 6)];
            M[x] = (int)((wv >> (5 * (vc % 6))) & 31u);
        }
    }
#pragma unroll
    for (int x = 0; x < NTAG; ++x) MLDS[l][x] = M[x];
    __syncthreads();

    if (l == 0) {
        int vc = best;
        ventry[63] = best;
        for (int c = 62; c >= 0; --c) { vc = MLDS[c + 1][vc]; ventry[c] = vc; }
    }
    __syncthreads();

    int x = ventry[l];
    if (l == 63) out[1 + T_LEN - 1] = (float)best;
    for (int t = hi; t >= lo; --t) {
        unsigned wv = bpsL[t*3 + (x / 6)];
        x = (int)((wv >> (5 * (x % 6))) & 31u);
        out[1 + t - 1] = (float)x;
    }
}

// ------------------------------------------------------------------ launch
extern "C" void kernel_launch(void* const* d_in, const int* in_sizes, int n_in,
                              void* d_out, int out_size, void* d_ws, size_t ws_size,
                              hipStream_t stream) {
    const int*   words = (const int*)  d_in[0];
    const float* h0    = (const float*)d_in[1];
    const float* c0    = (const float*)d_in[2];
    const float* emb   = (const float*)d_in[3];
    const float* Wih_f = (const float*)d_in[4];
    const float* Whh_f = (const float*)d_in[5];
    const float* b_f   = (const float*)d_in[6];
    const float* Wih_b = (const float*)d_in[7];
    const float* Whh_b = (const float*)d_in[8];
    const float* b_b   = (const float*)d_in[9];
    const float* Wout  = (const float*)d_in[10];
    const float* bout  = (const float*)d_in[11];
    const float* trans = (const float*)d_in[12];

    float* ws = (float*)d_ws;
    float* pre_f  = ws + OFF_PRE_F;
    float* pre_b  = ws + OFF_PRE_B;
    float* hs_f   = ws + OFF_HS_F;
    float* hs_b   = ws + OFF_HS_B;
    float* frames = ws + OFF_FRAMES;
    unsigned long long* mbox = (unsigned long long*)(ws + OFF_FRAMES); // dead before frames written
    float* out = (float*)d_out;

    hipLaunchKernelGGL(init_mbox_kernel, dim3(4), dim3(1024), 0, stream, mbox);
    hipLaunchKernelGGL(pre_gemm_kernel, dim3(32, 32, 2), dim3(256), 0, stream,
                       words, emb, Wih_f, b_f, Wih_b, b_b, pre_f, pre_b);
    hipLaunchKernelGGL(rec_kernel, dim3(256), dim3(512), 0, stream,
                       Whh_f, Whh_b, pre_f, pre_b, h0, c0, hs_f, hs_b, mbox);
    hipLaunchKernelGGL(frames_kernel, dim3(512), dim3(256), 0, stream,
                       hs_f, hs_b, Wout, bout, frames);
    hipLaunchKernelGGL(viterbi_kernel, dim3(1), dim3(64), 0, stream,
                       frames, trans, out);
}